// Round 2
// baseline (5375.553 us; speedup 1.0000x reference)
//
#include <hip/hip_runtime.h>
#include <hip/hip_bf16.h>
#include <hip/hip_cooperative_groups.h>
#include <math.h>

namespace cg = cooperative_groups;

#define BATCH 512
#define MAXL 128
#define HID 512
#define H3 1536

typedef __bf16 bf16x8 __attribute__((ext_vector_type(8)));
typedef __bf16 bf16x4 __attribute__((ext_vector_type(4)));
typedef float f32x4 __attribute__((ext_vector_type(4)));

// ---------------- prefix scan of lengths -> starts ----------------
__global__ __launch_bounds__(BATCH) void scan_kernel(const int* __restrict__ len,
                                                     int* __restrict__ starts) {
    __shared__ int buf[BATCH];
    int tid = threadIdx.x;
    int myLen = len[tid];
    buf[tid] = myLen;
    __syncthreads();
    for (int off = 1; off < BATCH; off <<= 1) {
        int v = (tid >= off) ? buf[tid - off] : 0;
        __syncthreads();
        buf[tid] += v;
        __syncthreads();
    }
    starts[tid] = buf[tid] - myLen;   // exclusive scan
}

// ------- h0 = segment_max(h) (fp32 + bf16 into scan buffer 0, both dirs) -------
__global__ __launch_bounds__(HID) void init_kernel(const float* __restrict__ h,
                                                   const int* __restrict__ len,
                                                   const int* __restrict__ starts,
                                                   float* __restrict__ h0,     // [B][H]
                                                   __bf16* __restrict__ hb) {  // buf0: [2][B][H]
    int b = blockIdx.x, j = threadIdx.x;
    int s = starts[b], L = len[b];
    float m = -3.4e38f;
    for (int t = 0; t < L; ++t) m = fmaxf(m, h[(size_t)(s + t) * HID + j]);
    h0[(size_t)b * HID + j] = m;
    hb[(size_t)b * HID + j] = (__bf16)m;
    hb[(size_t)(BATCH + b) * HID + j] = (__bf16)m;
}

// ---------------- message = relu(h + bias) -> bf16 ----------------
__global__ void msg_kernel(const float* __restrict__ h, const float* __restrict__ bias,
                           __bf16* __restrict__ msg, long total4) {
    for (long i = (long)blockIdx.x * blockDim.x + threadIdx.x; i < total4;
         i += (long)gridDim.x * blockDim.x) {
        float4 v = ((const float4*)h)[i];
        int c4 = (int)(i & (HID / 4 - 1));
        float4 bb = ((const float4*)bias)[c4];
        bf16x4 o;
        o[0] = (__bf16)fmaxf(v.x + bb.x, 0.f);
        o[1] = (__bf16)fmaxf(v.y + bb.y, 0.f);
        o[2] = (__bf16)fmaxf(v.z + bb.z, 0.f);
        o[3] = (__bf16)fmaxf(v.w + bb.w, 0.f);
        ((bf16x4*)msg)[i] = o;
    }
}

// ---------------- fp32 -> bf16 weight convert ----------------
__global__ void conv_kernel(const float* __restrict__ src, __bf16* __restrict__ dst, int n4) {
    int i = blockIdx.x * blockDim.x + threadIdx.x;
    if (i < n4) {
        float4 v = ((const float4*)src)[i];
        bf16x4 o;
        o[0] = (__bf16)v.x; o[1] = (__bf16)v.y; o[2] = (__bf16)v.z; o[3] = (__bf16)v.w;
        ((bf16x4*)dst)[i] = o;
    }
}

// ---------------- gx = msg @ w_ih^T  (NT GEMM, bf16 out, no bias) ----------------
__global__ __launch_bounds__(256) void gx_gemm(const __bf16* __restrict__ msg,
                                               const __bf16* __restrict__ wih,  // [2][1536][512]
                                               __bf16* __restrict__ gx,         // [2][N][1536]
                                               int N) {
    int dir = blockIdx.z;
    int wid = threadIdx.x >> 6, lane = threadIdx.x & 63;
    int r0 = blockIdx.y * 128 + (wid >> 1) * 64;
    int c0 = blockIdx.x * 128 + (wid & 1) * 64;
    int lrow = lane & 15, lk = (lane >> 4) * 8;
    const __bf16* wB = wih + (size_t)dir * H3 * HID;
    f32x4 acc[4][4] = {};
    for (int ks = 0; ks < HID; ks += 32) {
        bf16x8 a[4], b[4];
#pragma unroll
        for (int i = 0; i < 4; ++i) {
            int row = r0 + i * 16 + lrow; if (row >= N) row = N - 1;
            a[i] = *(const bf16x8*)(msg + (size_t)row * HID + ks + lk);
            b[i] = *(const bf16x8*)(wB + (size_t)(c0 + i * 16 + lrow) * HID + ks + lk);
        }
#pragma unroll
        for (int i = 0; i < 4; ++i)
#pragma unroll
            for (int j = 0; j < 4; ++j)
                acc[i][j] = __builtin_amdgcn_mfma_f32_16x16x32_bf16(a[i], b[j], acc[i][j], 0, 0, 0);
    }
    __bf16* gOut = gx + (size_t)dir * N * H3;
#pragma unroll
    for (int i = 0; i < 4; ++i)
#pragma unroll
        for (int j = 0; j < 4; ++j) {
            int col = c0 + j * 16 + (lane & 15);
#pragma unroll
            for (int reg = 0; reg < 4; ++reg) {
                int row = r0 + i * 16 + (lane >> 4) * 4 + reg;
                if (row < N) gOut[(size_t)row * H3 + col] = (__bf16)acc[i][j][reg];
            }
        }
}

// ================= persistent cooperative GRU scan =================
// 256 blocks x 256 threads, 1 block/CU. Block = (dir, rowGroup(8), hcolGroup(16)).
//   rg = bid & 7  -> blocks sharing rows land on one XCD (L2-local hb exchange).
// Block owns rows [rg*64, +64), hidden cols [hc*32, +32), all 3 gates, for all steps.
// whh tile (96KB) lives in LDS; fp32 state + sums live in registers.
__global__ __launch_bounds__(256, 1) void gru_scan(
    const __bf16* __restrict__ whh,   // [2][1536][512]
    const __bf16* __restrict__ gx,    // [2][N][1536]
    const float* __restrict__ h0,     // [B][H]
    __bf16* __restrict__ hb,          // [2 bufs][2 dirs][B][H]
    const float* __restrict__ b_ih_f, const float* __restrict__ b_hh_f,
    const float* __restrict__ b_ih_b, const float* __restrict__ b_hh_b,
    const int* __restrict__ len, const int* __restrict__ starts,
    float* __restrict__ out, int N) {

    __shared__ __bf16 wlds[96 * 512];   // 96KB: [gate*32+col][K], chunk-swizzled
    __shared__ __bf16 hout[64 * 32];    // 4KB repack tile

    int bid = blockIdx.x;
    int rg  = bid & 7;
    int dir = (bid >> 3) & 1;
    int hc  = bid >> 4;
    int wid = threadIdx.x >> 6, lane = threadIdx.x & 63;
    int r0 = rg * 64;
    int c0 = hc * 32;

    // ---- load whh tile into LDS with XOR-swizzled 16B chunks (one-time) ----
    for (int i = threadIdx.x; i < 96 * 64; i += 256) {
        int row = i >> 6;                 // 0..95  (gate*32 + colLocal)
        int ch  = i & 63;                 // 16B chunk within the 1024B row
        int g = row >> 5, c = row & 31;
        int sch = ch ^ (row & 7);
        const __bf16* src = whh + ((size_t)dir * H3 + (size_t)g * HID + c0 + c) * HID + ch * 8;
        *(bf16x8*)(&wlds[row * 512 + sch * 8]) = *(const bf16x8*)src;
    }

    int wr0 = r0 + wid * 16;              // this wave's 16 rows
    int lrow = lane & 15;
    int lk   = lane >> 4;                 // 0..3

    // per-lane output coordinates (C-frag layout: col = lane&15, row = (lane>>4)*4+reg)
    int mycol[2], myrow[4];
#pragma unroll
    for (int fj = 0; fj < 2; ++fj) mycol[fj] = c0 + fj * 16 + (lane & 15);
#pragma unroll
    for (int r = 0; r < 4; ++r) myrow[r] = wr0 + (lane >> 4) * 4 + r;

    float hreg[2][4], sreg[2][4];
#pragma unroll
    for (int fj = 0; fj < 2; ++fj)
#pragma unroll
        for (int r = 0; r < 4; ++r) {
            hreg[fj][r] = h0[(size_t)myrow[r] * HID + mycol[fj]];
            sreg[fj][r] = 0.f;
        }

    const float* bih = dir ? b_ih_b : b_ih_f;
    const float* bhh = dir ? b_hh_b : b_hh_f;
    float bihv[2][3], bhhv[2][3];
#pragma unroll
    for (int fj = 0; fj < 2; ++fj)
#pragma unroll
        for (int g = 0; g < 3; ++g) {
            bihv[fj][g] = bih[g * HID + mycol[fj]];
            bhhv[fj][g] = bhh[g * HID + mycol[fj]];
        }
    int mylen[4], mystart[4];
#pragma unroll
    for (int r = 0; r < 4; ++r) { mylen[r] = len[myrow[r]]; mystart[r] = starts[myrow[r]]; }

    cg::grid_group grid = cg::this_grid();
    __syncthreads();   // wlds ready

    const size_t bufStride = (size_t)2 * BATCH * HID;

    for (int s = 0; s < MAXL; ++s) {
        int t = dir ? (MAXL - 1 - s) : s;
        const __bf16* hcur = hb + (size_t)(s & 1) * bufStride + (size_t)dir * BATCH * HID;
        __bf16* hnxt = hb + (size_t)((s + 1) & 1) * bufStride + (size_t)dir * BATCH * HID;

        // ---- prefetch gx for the epilogue (independent of GEMM; hides HBM latency)
        float gxv[2][4][3];
#pragma unroll
        for (int r = 0; r < 4; ++r) {
            bool real = t < mylen[r];
            size_t base = ((size_t)dir * N + mystart[r] + t) * H3;
#pragma unroll
            for (int fj = 0; fj < 2; ++fj)
#pragma unroll
                for (int g = 0; g < 3; ++g)
                    gxv[fj][r][g] = real ? (float)gx[base + (size_t)g * HID + mycol[fj]] : 0.f;
        }

        // ---- prefetch A: 16 k-slices of this wave's [16 rows x 32 k]
        bf16x8 a[16];
#pragma unroll
        for (int ks = 0; ks < 16; ++ks)
            a[ks] = *(const bf16x8*)(hcur + (size_t)(wr0 + lrow) * HID + ks * 32 + lk * 8);

        // ---- GEMM: gh = h @ whh^T for 3 gates x 2 col-frags
        f32x4 acc[3][2] = {};
#pragma unroll
        for (int ks = 0; ks < 16; ++ks) {
#pragma unroll
            for (int g = 0; g < 3; ++g) {
#pragma unroll
                for (int f = 0; f < 2; ++f) {
                    int row = g * 32 + f * 16 + lrow;
                    int sch = (ks * 4 + lk) ^ (row & 7);
                    bf16x8 b = *(const bf16x8*)(&wlds[row * 512 + sch * 8]);
                    acc[g][f] = __builtin_amdgcn_mfma_f32_16x16x32_bf16(a[ks], b, acc[g][f], 0, 0, 0);
                }
            }
        }

        // ---- gate math + state update (fp32, in registers)
#pragma unroll
        for (int fj = 0; fj < 2; ++fj)
#pragma unroll
            for (int r = 0; r < 4; ++r) {
                float ghr = acc[0][fj][r] + bhhv[fj][0];
                float ghz = acc[1][fj][r] + bhhv[fj][1];
                float ghn = acc[2][fj][r] + bhhv[fj][2];
                float xr = gxv[fj][r][0] + bihv[fj][0];
                float xz = gxv[fj][r][1] + bihv[fj][1];
                float xn = gxv[fj][r][2] + bihv[fj][2];
                float rg_ = 1.f / (1.f + expf(-(xr + ghr)));
                float zg  = 1.f / (1.f + expf(-(xz + ghz)));
                float ng  = tanhf(xn + rg_ * ghn);
                float hn  = (1.f - zg) * ng + zg * hreg[fj][r];
                hreg[fj][r] = hn;
                if (t < mylen[r]) sreg[fj][r] += hn;
            }

        // ---- repack to bf16 rows via LDS, store coalesced to hnxt
#pragma unroll
        for (int fj = 0; fj < 2; ++fj)
#pragma unroll
            for (int r = 0; r < 4; ++r)
                hout[(wid * 16 + (lane >> 4) * 4 + r) * 32 + fj * 16 + (lane & 15)] =
                    (__bf16)hreg[fj][r];
        __syncthreads();
        {
            int row = threadIdx.x >> 2, ch = threadIdx.x & 3;
            *(bf16x8*)(hnxt + (size_t)(r0 + row) * HID + c0 + ch * 8) =
                *(const bf16x8*)(&hout[row * 32 + ch * 8]);
        }
        grid.sync();
    }

    // ---- final output: out[row][dir*H + col] = sum / len
#pragma unroll
    for (int fj = 0; fj < 2; ++fj)
#pragma unroll
        for (int r = 0; r < 4; ++r)
            out[(size_t)myrow[r] * (2 * HID) + (size_t)dir * HID + mycol[fj]] =
                sreg[fj][r] / (float)mylen[r];
}

extern "C" void kernel_launch(void* const* d_in, const int* in_sizes, int n_in,
                              void* d_out, int out_size, void* d_ws, size_t ws_size,
                              hipStream_t stream) {
    const float* h      = (const float*)d_in[0];
    const int*   lens   = (const int*)d_in[1];
    const float* bias   = (const float*)d_in[2];
    const float* w_ih_f = (const float*)d_in[3];
    const float* w_hh_f = (const float*)d_in[4];
    const float* b_ih_f = (const float*)d_in[5];
    const float* b_hh_f = (const float*)d_in[6];
    const float* w_ih_b = (const float*)d_in[7];
    const float* w_hh_b = (const float*)d_in[8];
    const float* b_ih_b = (const float*)d_in[9];
    const float* b_hh_b = (const float*)d_in[10];
    float* out = (float*)d_out;
    const int N = in_sizes[0] / HID;

    // workspace layout
    char* p = (char*)d_ws;
    size_t off = 0;
    int* starts = (int*)(p + off);          off += 4096;
    float* h0   = (float*)(p + off);        off += (size_t)BATCH * HID * 4;
    __bf16* hb  = (__bf16*)(p + off);       off += (size_t)2 * 2 * BATCH * HID * 2;
    __bf16* wih = (__bf16*)(p + off);       off += (size_t)2 * H3 * HID * 2;
    __bf16* whh = (__bf16*)(p + off);       off += (size_t)2 * H3 * HID * 2;
    __bf16* msg = (__bf16*)(p + off);       off += (size_t)N * HID * 2;
    __bf16* gx  = (__bf16*)(p + off);       off += (size_t)2 * N * H3 * 2;
    if (off > ws_size) return;  // interpretable failure: output stays zero

    scan_kernel<<<1, BATCH, 0, stream>>>(lens, starts);
    init_kernel<<<BATCH, HID, 0, stream>>>(h, lens, starts, h0, hb);

    long total4 = (long)N * HID / 4;
    int msgBlocks = (int)((total4 + 255) / 256); if (msgBlocks > 2048) msgBlocks = 2048;
    msg_kernel<<<msgBlocks, 256, 0, stream>>>(h, bias, msg, total4);

    int n4 = H3 * HID / 4;
    int cb = (n4 + 255) / 256;
    conv_kernel<<<cb, 256, 0, stream>>>(w_ih_f, wih, n4);
    conv_kernel<<<cb, 256, 0, stream>>>(w_ih_b, wih + (size_t)H3 * HID, n4);
    conv_kernel<<<cb, 256, 0, stream>>>(w_hh_f, whh, n4);
    conv_kernel<<<cb, 256, 0, stream>>>(w_hh_b, whh + (size_t)H3 * HID, n4);

    gx_gemm<<<dim3(12, (N + 127) / 128, 2), 256, 0, stream>>>(msg, wih, gx, N);

    int Nv = N;
    void* kargs[] = {(void*)&whh, (void*)&gx, (void*)&h0, (void*)&hb,
                     (void*)&b_ih_f, (void*)&b_hh_f, (void*)&b_ih_b, (void*)&b_hh_b,
                     (void*)&lens, (void*)&starts, (void*)&out, (void*)&Nv};
    hipLaunchCooperativeKernel((const void*)gru_scan, dim3(256), dim3(256), kargs, 0, stream);
}

// Round 4
// 2435.515 us; speedup vs baseline: 2.2072x; 2.2072x over previous
//
#include <hip/hip_runtime.h>
#include <hip/hip_bf16.h>
#include <math.h>

#define BATCH 512
#define MAXL 128
#define HID 512
#define H3 1536

typedef __bf16 bf16x8 __attribute__((ext_vector_type(8)));
typedef __bf16 bf16x4 __attribute__((ext_vector_type(4)));
typedef float f32x4 __attribute__((ext_vector_type(4)));

// agent-scope (device-coherent, fine-grained) 8B load/store — bypass stale L1/L2,
// meet at the coherence point; no full L2 flush needed.
__device__ __forceinline__ void st_agent8(void* p, unsigned long long v) {
    __hip_atomic_store((unsigned long long*)p, v, __ATOMIC_RELAXED, __HIP_MEMORY_SCOPE_AGENT);
}
__device__ __forceinline__ unsigned long long ld_agent8(const void* p) {
    return __hip_atomic_load((const unsigned long long*)p, __ATOMIC_RELAXED, __HIP_MEMORY_SCOPE_AGENT);
}

// ---------------- prefix scan of lengths -> starts; zero barrier counters ----------------
__global__ __launch_bounds__(BATCH) void scan_kernel(const int* __restrict__ len,
                                                     int* __restrict__ starts,
                                                     unsigned* __restrict__ ctr) {
    __shared__ int buf[BATCH];
    int tid = threadIdx.x;
    ctr[tid] = 0u;                    // re-zeroed every launch (determinism across replays)
    int myLen = len[tid];
    buf[tid] = myLen;
    __syncthreads();
    for (int off = 1; off < BATCH; off <<= 1) {
        int v = (tid >= off) ? buf[tid - off] : 0;
        __syncthreads();
        buf[tid] += v;
        __syncthreads();
    }
    starts[tid] = buf[tid] - myLen;   // exclusive scan
}

// ------- h0 = segment_max(h) (fp32 + bf16 into scan buffer 0, both dirs) -------
__global__ __launch_bounds__(HID) void init_kernel(const float* __restrict__ h,
                                                   const int* __restrict__ len,
                                                   const int* __restrict__ starts,
                                                   float* __restrict__ h0,     // [B][H]
                                                   __bf16* __restrict__ hb) {  // buf0: [2][B][H]
    int b = blockIdx.x, j = threadIdx.x;
    int s = starts[b], L = len[b];
    float m = -3.4e38f;
    for (int t = 0; t < L; ++t) m = fmaxf(m, h[(size_t)(s + t) * HID + j]);
    h0[(size_t)b * HID + j] = m;
    hb[(size_t)b * HID + j] = (__bf16)m;
    hb[(size_t)(BATCH + b) * HID + j] = (__bf16)m;
}

// ---------------- message = relu(h + bias) -> bf16 ----------------
__global__ void msg_kernel(const float* __restrict__ h, const float* __restrict__ bias,
                           __bf16* __restrict__ msg, long total4) {
    for (long i = (long)blockIdx.x * blockDim.x + threadIdx.x; i < total4;
         i += (long)gridDim.x * blockDim.x) {
        float4 v = ((const float4*)h)[i];
        int c4 = (int)(i & (HID / 4 - 1));
        float4 bb = ((const float4*)bias)[c4];
        bf16x4 o;
        o[0] = (__bf16)fmaxf(v.x + bb.x, 0.f);
        o[1] = (__bf16)fmaxf(v.y + bb.y, 0.f);
        o[2] = (__bf16)fmaxf(v.z + bb.z, 0.f);
        o[3] = (__bf16)fmaxf(v.w + bb.w, 0.f);
        ((bf16x4*)msg)[i] = o;
    }
}

// ---------------- fp32 -> bf16 weight convert ----------------
__global__ void conv_kernel(const float* __restrict__ src, __bf16* __restrict__ dst, int n4) {
    int i = blockIdx.x * blockDim.x + threadIdx.x;
    if (i < n4) {
        float4 v = ((const float4*)src)[i];
        bf16x4 o;
        o[0] = (__bf16)v.x; o[1] = (__bf16)v.y; o[2] = (__bf16)v.z; o[3] = (__bf16)v.w;
        ((bf16x4*)dst)[i] = o;
    }
}

// ---------------- gx = msg @ w_ih^T  (NT GEMM, bf16 out) ----------------
// grid (ceil(N/64), 2dirs), block 256. Block owns 64 rows x all 1536 cols:
// msg read ONCE (A staged swizzled in LDS), cols split across waves so whh is
// read once per block (L2-resident), stores coalesced via LDS repack tile.
__global__ __launch_bounds__(256) void gx_gemm(const __bf16* __restrict__ msg,
                                               const __bf16* __restrict__ wih,  // [2][1536][512]
                                               __bf16* __restrict__ gx,         // [2][N][1536]
                                               int N) {
    __shared__ __bf16 alds[64 * 512];    // 64KB, rows of 1KB, 16B-chunk XOR swizzle
    __shared__ __bf16 tile[64][136];     // 17KB output repack (row stride 272B, 16B-aligned)
    int dir = blockIdx.y;
    int r0 = blockIdx.x * 64;
    int wid = threadIdx.x >> 6, lane = threadIdx.x & 63;
    int lrow = lane & 15, lk = lane >> 4;
    const __bf16* wB = wih + (size_t)dir * H3 * HID;
    __bf16* gOut = gx + (size_t)dir * N * H3;

    // stage A (64 rows x 512 K) with swizzled 16B chunks
    for (int i = threadIdx.x; i < 64 * 64; i += 256) {
        int row = i >> 6, ch = i & 63;
        int sch = ch ^ (row & 7);
        int grow = r0 + row; if (grow >= N) grow = N - 1;
        *(bf16x8*)(&alds[row * 512 + sch * 8]) = *(const bf16x8*)(msg + (size_t)grow * HID + ch * 8);
    }
    __syncthreads();

    for (int ct = 0; ct < 12; ++ct) {
        int c0 = ct * 128 + wid * 32;    // this wave's 32 output cols
        f32x4 acc[4][2] = {};            // 4 row-frags x 2 col-frags
#pragma unroll
        for (int ks = 0; ks < 16; ++ks) {
            bf16x8 b0 = *(const bf16x8*)(wB + (size_t)(c0 + lrow) * HID + ks * 32 + lk * 8);
            bf16x8 b1 = *(const bf16x8*)(wB + (size_t)(c0 + 16 + lrow) * HID + ks * 32 + lk * 8);
#pragma unroll
            for (int rf = 0; rf < 4; ++rf) {
                int row = rf * 16 + lrow;
                int sch = (ks * 4 + lk) ^ (row & 7);
                bf16x8 av = *(const bf16x8*)(&alds[row * 512 + sch * 8]);
                acc[rf][0] = __builtin_amdgcn_mfma_f32_16x16x32_bf16(av, b0, acc[rf][0], 0, 0, 0);
                acc[rf][1] = __builtin_amdgcn_mfma_f32_16x16x32_bf16(av, b1, acc[rf][1], 0, 0, 0);
            }
        }
        __syncthreads();   // tile free from previous ct's readers
#pragma unroll
        for (int rf = 0; rf < 4; ++rf)
#pragma unroll
            for (int fj = 0; fj < 2; ++fj)
#pragma unroll
                for (int r = 0; r < 4; ++r)
                    tile[rf * 16 + (lane >> 4) * 4 + r][wid * 32 + fj * 16 + (lane & 15)] =
                        (__bf16)acc[rf][fj][r];
        __syncthreads();
        // 256 threads = 64 rows x 4 chunks of 32 cols; each thread writes ALL 32 cols
        int row = threadIdx.x >> 2, ch = threadIdx.x & 3;
        if (r0 + row < N) {
            __bf16* d = gOut + (size_t)(r0 + row) * H3 + ct * 128 + ch * 32;
            *(bf16x8*)(d)      = *(const bf16x8*)(&tile[row][ch * 32]);
            *(bf16x8*)(d + 8)  = *(const bf16x8*)(&tile[row][ch * 32 + 8]);
            *(bf16x8*)(d + 16) = *(const bf16x8*)(&tile[row][ch * 32 + 16]);
            *(bf16x8*)(d + 24) = *(const bf16x8*)(&tile[row][ch * 32 + 24]);
        }
    }
}

// ================= persistent GRU scan, custom 16-block barriers =================
// 256 blocks x 256 threads (coop launch for co-residency). Block = (dir, rg(8), hc(16)).
// Sync group = {dir, rg}: the 16 col-blocks sharing rows. Monotone counter barrier;
// h exchange via agent-scope 8B atomics (fine-grained coherent, no L2 flush).
__global__ __launch_bounds__(256, 1) void gru_scan(
    const __bf16* __restrict__ whh,   // [2][1536][512]
    const __bf16* __restrict__ gx,    // [2][N][1536]
    const float* __restrict__ h0,     // [B][H]
    __bf16* __restrict__ hb,          // [2 bufs][2 dirs][B][H]
    const float* __restrict__ b_ih_f, const float* __restrict__ b_hh_f,
    const float* __restrict__ b_ih_b, const float* __restrict__ b_hh_b,
    const int* __restrict__ len, const int* __restrict__ starts,
    unsigned* __restrict__ ctr,       // [16 groups] spaced 32 dwords apart
    float* __restrict__ out, int N) {

    __shared__ __bf16 wlds[96 * 512];   // 96KB weight tile, 16B-chunk XOR swizzle
    __shared__ __bf16 hout[64 * 32];    // 4KB repack tile

    int bid = blockIdx.x;
    int rg  = bid & 7;                  // same rg -> same XCD (heuristic; not required)
    int dir = (bid >> 3) & 1;
    int hc  = bid >> 4;
    int grp = dir * 8 + rg;
    int wid = threadIdx.x >> 6, lane = threadIdx.x & 63;
    int r0 = rg * 64;
    int c0 = hc * 32;

    for (int i = threadIdx.x; i < 96 * 64; i += 256) {
        int row = i >> 6, ch = i & 63;
        int g = row >> 5, c = row & 31;
        int sch = ch ^ (row & 7);
        const __bf16* src = whh + ((size_t)dir * H3 + (size_t)g * HID + c0 + c) * HID + ch * 8;
        *(bf16x8*)(&wlds[row * 512 + sch * 8]) = *(const bf16x8*)src;
    }

    int wr0 = r0 + wid * 16;
    int lrow = lane & 15;
    int lk   = lane >> 4;

    int mycol[2], myrow[4];
#pragma unroll
    for (int fj = 0; fj < 2; ++fj) mycol[fj] = c0 + fj * 16 + (lane & 15);
#pragma unroll
    for (int r = 0; r < 4; ++r) myrow[r] = wr0 + (lane >> 4) * 4 + r;

    float hreg[2][4], sreg[2][4];
#pragma unroll
    for (int fj = 0; fj < 2; ++fj)
#pragma unroll
        for (int r = 0; r < 4; ++r) {
            hreg[fj][r] = h0[(size_t)myrow[r] * HID + mycol[fj]];
            sreg[fj][r] = 0.f;
        }

    const float* bih = dir ? b_ih_b : b_ih_f;
    const float* bhh = dir ? b_hh_b : b_hh_f;
    float bihv[2][3], bhhv[2][3];
#pragma unroll
    for (int fj = 0; fj < 2; ++fj)
#pragma unroll
        for (int g = 0; g < 3; ++g) {
            bihv[fj][g] = bih[g * HID + mycol[fj]];
            bhhv[fj][g] = bhh[g * HID + mycol[fj]];
        }
    int mylen[4], mystart[4];
#pragma unroll
    for (int r = 0; r < 4; ++r) { mylen[r] = len[myrow[r]]; mystart[r] = starts[myrow[r]]; }

    // prefetch gx for step 0
    float gxv[2][4][3];
    {
        int t = dir ? (MAXL - 1) : 0;
#pragma unroll
        for (int r = 0; r < 4; ++r) {
            bool real = t < mylen[r];
            size_t base = ((size_t)dir * N + mystart[r] + t) * H3;
#pragma unroll
            for (int fj = 0; fj < 2; ++fj)
#pragma unroll
                for (int g = 0; g < 3; ++g)
                    gxv[fj][r][g] = real ? (float)gx[base + (size_t)g * HID + mycol[fj]] : 0.f;
        }
    }

    __syncthreads();   // wlds ready

    const size_t bufStride = (size_t)2 * BATCH * HID;

    for (int s = 0; s < MAXL; ++s) {
        int t = dir ? (MAXL - 1 - s) : s;
        const __bf16* hcur = hb + (size_t)(s & 1) * bufStride + (size_t)dir * BATCH * HID;
        __bf16* hnxt = hb + (size_t)((s + 1) & 1) * bufStride + (size_t)dir * BATCH * HID;

        // ---- A: this wave's [16 rows x 512 K] via coherent 8B loads
        bf16x8 a[16];
#pragma unroll
        for (int ks = 0; ks < 16; ++ks) {
            const char* p = (const char*)(hcur + (size_t)(wr0 + lrow) * HID + ks * 32 + lk * 8);
            union { unsigned long long u[2]; bf16x8 v; } u;
            u.u[0] = ld_agent8(p);
            u.u[1] = ld_agent8(p + 8);
            a[ks] = u.v;
        }

        // ---- GEMM: gh = h @ whh^T, 3 gates x 2 col-frags
        f32x4 acc[3][2] = {};
#pragma unroll
        for (int ks = 0; ks < 16; ++ks) {
#pragma unroll
            for (int g = 0; g < 3; ++g) {
#pragma unroll
                for (int f = 0; f < 2; ++f) {
                    int row = g * 32 + f * 16 + lrow;
                    int sch = (ks * 4 + lk) ^ (row & 7);
                    bf16x8 b = *(const bf16x8*)(&wlds[row * 512 + sch * 8]);
                    acc[g][f] = __builtin_amdgcn_mfma_f32_16x16x32_bf16(a[ks], b, acc[g][f], 0, 0, 0);
                }
            }
        }

        // ---- gate math + state update (fp32, registers)
#pragma unroll
        for (int fj = 0; fj < 2; ++fj)
#pragma unroll
            for (int r = 0; r < 4; ++r) {
                float ghr = acc[0][fj][r] + bhhv[fj][0];
                float ghz = acc[1][fj][r] + bhhv[fj][1];
                float ghn = acc[2][fj][r] + bhhv[fj][2];
                float xr = gxv[fj][r][0] + bihv[fj][0];
                float xz = gxv[fj][r][1] + bihv[fj][1];
                float xn = gxv[fj][r][2] + bihv[fj][2];
                float rg_ = 1.f / (1.f + expf(-(xr + ghr)));
                float zg  = 1.f / (1.f + expf(-(xz + ghz)));
                float ng  = tanhf(xn + rg_ * ghn);
                float hn  = (1.f - zg) * ng + zg * hreg[fj][r];
                hreg[fj][r] = hn;
                if (t < mylen[r]) sreg[fj][r] += hn;
            }

        // ---- repack to rows in LDS, then coherent 8B stores to hnxt
#pragma unroll
        for (int fj = 0; fj < 2; ++fj)
#pragma unroll
            for (int r = 0; r < 4; ++r)
                hout[(wid * 16 + (lane >> 4) * 4 + r) * 32 + fj * 16 + (lane & 15)] =
                    (__bf16)hreg[fj][r];
        __syncthreads();
        {
            int row = threadIdx.x >> 2, ch = threadIdx.x & 3;
            unsigned long long* dst =
                (unsigned long long*)(hnxt + (size_t)(r0 + row) * HID + c0 + ch * 8);
            const unsigned long long* src = (const unsigned long long*)&hout[row * 32 + ch * 8];
            st_agent8(dst, src[0]);
            st_agent8(dst + 1, src[1]);
        }
        if (s + 1 == MAXL) break;   // no barrier needed after last step

        // all waves' coherent stores drain (vmcnt) before any wave passes this barrier
        __syncthreads();
        if (threadIdx.x == 0)
            __hip_atomic_fetch_add(ctr + grp * 32, 1u, __ATOMIC_RELEASE, __HIP_MEMORY_SCOPE_AGENT);

        // prefetch next step's gx while waiting (independent of the exchange)
        {
            int tn = dir ? (MAXL - 2 - s) : (s + 1);
#pragma unroll
            for (int r = 0; r < 4; ++r) {
                bool real = tn < mylen[r];
                size_t base = ((size_t)dir * N + mystart[r] + tn) * H3;
#pragma unroll
                for (int fj = 0; fj < 2; ++fj)
#pragma unroll
                    for (int g = 0; g < 3; ++g)
                        gxv[fj][r][g] = real ? (float)gx[base + (size_t)g * HID + mycol[fj]] : 0.f;
            }
        }

        if (threadIdx.x == 0) {
            unsigned tgt = 16u * (unsigned)(s + 1);
            while (__hip_atomic_load(ctr + grp * 32, __ATOMIC_ACQUIRE,
                                     __HIP_MEMORY_SCOPE_AGENT) < tgt)
                __builtin_amdgcn_s_sleep(1);
        }
        __syncthreads();
        __builtin_amdgcn_sched_barrier(0);   // keep next A-loads after the spin exit
    }

    // ---- final output: out[row][dir*H + col] = sum / len
#pragma unroll
    for (int fj = 0; fj < 2; ++fj)
#pragma unroll
        for (int r = 0; r < 4; ++r)
            out[(size_t)myrow[r] * (2 * HID) + (size_t)dir * HID + mycol[fj]] =
                sreg[fj][r] / (float)mylen[r];
}

extern "C" void kernel_launch(void* const* d_in, const int* in_sizes, int n_in,
                              void* d_out, int out_size, void* d_ws, size_t ws_size,
                              hipStream_t stream) {
    const float* h      = (const float*)d_in[0];
    const int*   lens   = (const int*)d_in[1];
    const float* bias   = (const float*)d_in[2];
    const float* w_ih_f = (const float*)d_in[3];
    const float* w_hh_f = (const float*)d_in[4];
    const float* b_ih_f = (const float*)d_in[5];
    const float* b_hh_f = (const float*)d_in[6];
    const float* w_ih_b = (const float*)d_in[7];
    const float* w_hh_b = (const float*)d_in[8];
    const float* b_ih_b = (const float*)d_in[9];
    const float* b_hh_b = (const float*)d_in[10];
    float* out = (float*)d_out;
    const int N = in_sizes[0] / HID;

    // workspace layout
    char* p = (char*)d_ws;
    size_t off = 0;
    int* starts   = (int*)(p + off);        off += 4096;
    unsigned* ctr = (unsigned*)(p + off);   off += 4096;   // 512 u32, groups 128B apart
    float* h0   = (float*)(p + off);        off += (size_t)BATCH * HID * 4;
    __bf16* hb  = (__bf16*)(p + off);       off += (size_t)2 * 2 * BATCH * HID * 2;
    __bf16* wih = (__bf16*)(p + off);       off += (size_t)2 * H3 * HID * 2;
    __bf16* whh = (__bf16*)(p + off);       off += (size_t)2 * H3 * HID * 2;
    __bf16* msg = (__bf16*)(p + off);       off += (size_t)N * HID * 2;
    __bf16* gx  = (__bf16*)(p + off);       off += (size_t)2 * N * H3 * 2;
    if (off > ws_size) return;  // interpretable failure: output stays zero

    scan_kernel<<<1, BATCH, 0, stream>>>(lens, starts, ctr);
    init_kernel<<<BATCH, HID, 0, stream>>>(h, lens, starts, h0, hb);

    long total4 = (long)N * HID / 4;
    int msgBlocks = (int)((total4 + 255) / 256); if (msgBlocks > 2048) msgBlocks = 2048;
    msg_kernel<<<msgBlocks, 256, 0, stream>>>(h, bias, msg, total4);

    int n4 = H3 * HID / 4;
    int cb = (n4 + 255) / 256;
    conv_kernel<<<cb, 256, 0, stream>>>(w_ih_f, wih, n4);
    conv_kernel<<<cb, 256, 0, stream>>>(w_ih_b, wih + (size_t)H3 * HID, n4);
    conv_kernel<<<cb, 256, 0, stream>>>(w_hh_f, whh, n4);
    conv_kernel<<<cb, 256, 0, stream>>>(w_hh_b, whh + (size_t)H3 * HID, n4);

    gx_gemm<<<dim3((N + 63) / 64, 2), 256, 0, stream>>>(msg, wih, gx, N);

    int Nv = N;
    void* kargs[] = {(void*)&whh, (void*)&gx, (void*)&h0, (void*)&hb,
                     (void*)&b_ih_f, (void*)&b_hh_f, (void*)&b_ih_b, (void*)&b_hh_b,
                     (void*)&lens, (void*)&starts, (void*)&ctr, (void*)&out, (void*)&Nv};
    hipLaunchCooperativeKernel((const void*)gru_scan, dim3(256), dim3(256), kargs, 0, stream);
}

// Round 5
// 1927.931 us; speedup vs baseline: 2.7882x; 1.2633x over previous
//
#include <hip/hip_runtime.h>
#include <hip/hip_bf16.h>
#include <math.h>

#define BATCH 512
#define MAXL 128
#define HID 512
#define H3 1536

typedef __bf16 bf16x8 __attribute__((ext_vector_type(8)));
typedef __bf16 bf16x4 __attribute__((ext_vector_type(4)));
typedef float f32x4 __attribute__((ext_vector_type(4)));

// agent-scope (device-coherent, fine-grained) 8B load/store — bypass stale L1/L2,
// meet at the coherence point; RELAXED only (no acquire/release: those emit
// buffer_inv/buffer_wbl2 L2 maintenance on gfx950 — measured 80MB/step refetch).
__device__ __forceinline__ void st_agent8(void* p, unsigned long long v) {
    __hip_atomic_store((unsigned long long*)p, v, __ATOMIC_RELAXED, __HIP_MEMORY_SCOPE_AGENT);
}
__device__ __forceinline__ unsigned long long ld_agent8(const void* p) {
    return __hip_atomic_load((const unsigned long long*)p, __ATOMIC_RELAXED, __HIP_MEMORY_SCOPE_AGENT);
}

// ---------------- prefix scan of lengths -> starts; zero barrier counters ----------------
__global__ __launch_bounds__(BATCH) void scan_kernel(const int* __restrict__ len,
                                                     int* __restrict__ starts,
                                                     unsigned* __restrict__ ctr) {
    __shared__ int buf[BATCH];
    int tid = threadIdx.x;
    ctr[tid] = 0u;                    // re-zeroed every launch (determinism across replays)
    int myLen = len[tid];
    buf[tid] = myLen;
    __syncthreads();
    for (int off = 1; off < BATCH; off <<= 1) {
        int v = (tid >= off) ? buf[tid - off] : 0;
        __syncthreads();
        buf[tid] += v;
        __syncthreads();
    }
    starts[tid] = buf[tid] - myLen;   // exclusive scan
}

// ------- h0 = segment_max(h) (fp32 + bf16 into scan buffer 0, both dirs) -------
__global__ __launch_bounds__(HID) void init_kernel(const float* __restrict__ h,
                                                   const int* __restrict__ len,
                                                   const int* __restrict__ starts,
                                                   float* __restrict__ h0,     // [B][H]
                                                   __bf16* __restrict__ hb) {  // buf0: [2][B][H]
    int b = blockIdx.x, j = threadIdx.x;
    int s = starts[b], L = len[b];
    float m = -3.4e38f;
    for (int t = 0; t < L; ++t) m = fmaxf(m, h[(size_t)(s + t) * HID + j]);
    h0[(size_t)b * HID + j] = m;
    hb[(size_t)b * HID + j] = (__bf16)m;
    hb[(size_t)(BATCH + b) * HID + j] = (__bf16)m;
}

// ---------------- message = relu(h + bias) -> bf16 ----------------
__global__ void msg_kernel(const float* __restrict__ h, const float* __restrict__ bias,
                           __bf16* __restrict__ msg, long total4) {
    for (long i = (long)blockIdx.x * blockDim.x + threadIdx.x; i < total4;
         i += (long)gridDim.x * blockDim.x) {
        float4 v = ((const float4*)h)[i];
        int c4 = (int)(i & (HID / 4 - 1));
        float4 bb = ((const float4*)bias)[c4];
        bf16x4 o;
        o[0] = (__bf16)fmaxf(v.x + bb.x, 0.f);
        o[1] = (__bf16)fmaxf(v.y + bb.y, 0.f);
        o[2] = (__bf16)fmaxf(v.z + bb.z, 0.f);
        o[3] = (__bf16)fmaxf(v.w + bb.w, 0.f);
        ((bf16x4*)msg)[i] = o;
    }
}

// ---------------- fp32 -> bf16 weight convert ----------------
__global__ void conv_kernel(const float* __restrict__ src, __bf16* __restrict__ dst, int n4) {
    int i = blockIdx.x * blockDim.x + threadIdx.x;
    if (i < n4) {
        float4 v = ((const float4*)src)[i];
        bf16x4 o;
        o[0] = (__bf16)v.x; o[1] = (__bf16)v.y; o[2] = (__bf16)v.z; o[3] = (__bf16)v.w;
        ((bf16x4*)dst)[i] = o;
    }
}

// ---------------- gx = msg @ w_ih^T  (NT GEMM, bf16 out) ----------------
// grid (ceil(N/64), 2dirs), block 256. Block owns 64 rows x all 1536 cols:
// msg read ONCE (A staged swizzled in LDS), cols split across waves so whh is
// read once per block (L2-resident), stores coalesced via LDS repack tile.
__global__ __launch_bounds__(256) void gx_gemm(const __bf16* __restrict__ msg,
                                               const __bf16* __restrict__ wih,  // [2][1536][512]
                                               __bf16* __restrict__ gx,         // [2][N][1536]
                                               int N) {
    __shared__ __bf16 alds[64 * 512];    // 64KB, rows of 1KB, 16B-chunk XOR swizzle
    __shared__ __bf16 tile[64][136];     // 17KB output repack (row stride 272B, 16B-aligned)
    int dir = blockIdx.y;
    int r0 = blockIdx.x * 64;
    int wid = threadIdx.x >> 6, lane = threadIdx.x & 63;
    int lrow = lane & 15, lk = lane >> 4;
    const __bf16* wB = wih + (size_t)dir * H3 * HID;
    __bf16* gOut = gx + (size_t)dir * N * H3;

    // stage A (64 rows x 512 K) with swizzled 16B chunks
    for (int i = threadIdx.x; i < 64 * 64; i += 256) {
        int row = i >> 6, ch = i & 63;
        int sch = ch ^ (row & 7);
        int grow = r0 + row; if (grow >= N) grow = N - 1;
        *(bf16x8*)(&alds[row * 512 + sch * 8]) = *(const bf16x8*)(msg + (size_t)grow * HID + ch * 8);
    }
    __syncthreads();

    for (int ct = 0; ct < 12; ++ct) {
        int c0 = ct * 128 + wid * 32;    // this wave's 32 output cols
        f32x4 acc[4][2] = {};            // 4 row-frags x 2 col-frags
#pragma unroll
        for (int ks = 0; ks < 16; ++ks) {
            bf16x8 b0 = *(const bf16x8*)(wB + (size_t)(c0 + lrow) * HID + ks * 32 + lk * 8);
            bf16x8 b1 = *(const bf16x8*)(wB + (size_t)(c0 + 16 + lrow) * HID + ks * 32 + lk * 8);
#pragma unroll
            for (int rf = 0; rf < 4; ++rf) {
                int row = rf * 16 + lrow;
                int sch = (ks * 4 + lk) ^ (row & 7);
                bf16x8 av = *(const bf16x8*)(&alds[row * 512 + sch * 8]);
                acc[rf][0] = __builtin_amdgcn_mfma_f32_16x16x32_bf16(av, b0, acc[rf][0], 0, 0, 0);
                acc[rf][1] = __builtin_amdgcn_mfma_f32_16x16x32_bf16(av, b1, acc[rf][1], 0, 0, 0);
            }
        }
        __syncthreads();   // tile free from previous ct's readers
#pragma unroll
        for (int rf = 0; rf < 4; ++rf)
#pragma unroll
            for (int fj = 0; fj < 2; ++fj)
#pragma unroll
                for (int r = 0; r < 4; ++r)
                    tile[rf * 16 + (lane >> 4) * 4 + r][wid * 32 + fj * 16 + (lane & 15)] =
                        (__bf16)acc[rf][fj][r];
        __syncthreads();
        // 256 threads = 64 rows x 4 chunks of 32 cols; each thread writes ALL 32 cols
        int row = threadIdx.x >> 2, ch = threadIdx.x & 3;
        if (r0 + row < N) {
            __bf16* d = gOut + (size_t)(r0 + row) * H3 + ct * 128 + ch * 32;
            *(bf16x8*)(d)      = *(const bf16x8*)(&tile[row][ch * 32]);
            *(bf16x8*)(d + 8)  = *(const bf16x8*)(&tile[row][ch * 32 + 8]);
            *(bf16x8*)(d + 16) = *(const bf16x8*)(&tile[row][ch * 32 + 16]);
            *(bf16x8*)(d + 24) = *(const bf16x8*)(&tile[row][ch * 32 + 24]);
        }
    }
}

// ================= persistent GRU scan, custom 16-block barriers =================
// 256 blocks x 256 threads (coop launch for co-residency). Block = (dir, rg(8), hc(16)).
// Sync group = {dir, rg}: the 16 col-blocks sharing rows. Monotone counter barrier,
// ALL-RELAXED atomics: ordering comes from (a) __syncthreads' vmcnt(0) drain before
// the arrive-add (stores globally visible first) and (b) control dep + sched/compiler
// barriers after the poll. No acquire/release -> no buffer_inv/wbl2 L2 thrash.
__global__ __launch_bounds__(256, 1) void gru_scan(
    const __bf16* __restrict__ whh,   // [2][1536][512]
    const __bf16* __restrict__ gx,    // [2][N][1536]
    const float* __restrict__ h0,     // [B][H]
    __bf16* __restrict__ hb,          // [2 bufs][2 dirs][B][H]
    const float* __restrict__ b_ih_f, const float* __restrict__ b_hh_f,
    const float* __restrict__ b_ih_b, const float* __restrict__ b_hh_b,
    const int* __restrict__ len, const int* __restrict__ starts,
    unsigned* __restrict__ ctr,       // [16 groups] spaced 32 dwords apart
    float* __restrict__ out, int N) {

    __shared__ __bf16 wlds[96 * 512];   // 96KB weight tile, 16B-chunk XOR swizzle
    __shared__ __bf16 hout[64 * 32];    // 4KB repack tile

    int bid = blockIdx.x;
    int rg  = bid & 7;                  // same rg -> same XCD (heuristic; not required)
    int dir = (bid >> 3) & 1;
    int hc  = bid >> 4;
    int grp = dir * 8 + rg;
    int wid = threadIdx.x >> 6, lane = threadIdx.x & 63;
    int r0 = rg * 64;
    int c0 = hc * 32;

    for (int i = threadIdx.x; i < 96 * 64; i += 256) {
        int row = i >> 6, ch = i & 63;
        int g = row >> 5, c = row & 31;
        int sch = ch ^ (row & 7);
        const __bf16* src = whh + ((size_t)dir * H3 + (size_t)g * HID + c0 + c) * HID + ch * 8;
        *(bf16x8*)(&wlds[row * 512 + sch * 8]) = *(const bf16x8*)src;
    }

    int wr0 = r0 + wid * 16;
    int lrow = lane & 15;
    int lk   = lane >> 4;

    int mycol[2], myrow[4];
#pragma unroll
    for (int fj = 0; fj < 2; ++fj) mycol[fj] = c0 + fj * 16 + (lane & 15);
#pragma unroll
    for (int r = 0; r < 4; ++r) myrow[r] = wr0 + (lane >> 4) * 4 + r;

    float hreg[2][4], sreg[2][4];
#pragma unroll
    for (int fj = 0; fj < 2; ++fj)
#pragma unroll
        for (int r = 0; r < 4; ++r) {
            hreg[fj][r] = h0[(size_t)myrow[r] * HID + mycol[fj]];
            sreg[fj][r] = 0.f;
        }

    const float* bih = dir ? b_ih_b : b_ih_f;
    const float* bhh = dir ? b_hh_b : b_hh_f;
    float bihv[2][3], bhhv[2][3];
#pragma unroll
    for (int fj = 0; fj < 2; ++fj)
#pragma unroll
        for (int g = 0; g < 3; ++g) {
            bihv[fj][g] = bih[g * HID + mycol[fj]];
            bhhv[fj][g] = bhh[g * HID + mycol[fj]];
        }
    int mylen[4], mystart[4];
#pragma unroll
    for (int r = 0; r < 4; ++r) { mylen[r] = len[myrow[r]]; mystart[r] = starts[myrow[r]]; }

    // prefetch gx for step 0
    float gxv[2][4][3];
    {
        int t = dir ? (MAXL - 1) : 0;
#pragma unroll
        for (int r = 0; r < 4; ++r) {
            bool real = t < mylen[r];
            size_t base = ((size_t)dir * N + mystart[r] + t) * H3;
#pragma unroll
            for (int fj = 0; fj < 2; ++fj)
#pragma unroll
                for (int g = 0; g < 3; ++g)
                    gxv[fj][r][g] = real ? (float)gx[base + (size_t)g * HID + mycol[fj]] : 0.f;
        }
    }

    __syncthreads();   // wlds ready

    const size_t bufStride = (size_t)2 * BATCH * HID;

    for (int s = 0; s < MAXL; ++s) {
        int t = dir ? (MAXL - 1 - s) : s;
        const __bf16* hcur = hb + (size_t)(s & 1) * bufStride + (size_t)dir * BATCH * HID;
        __bf16* hnxt = hb + (size_t)((s + 1) & 1) * bufStride + (size_t)dir * BATCH * HID;

        // ---- A: this wave's [16 rows x 512 K] via coherent 8B loads
        bf16x8 a[16];
#pragma unroll
        for (int ks = 0; ks < 16; ++ks) {
            const char* p = (const char*)(hcur + (size_t)(wr0 + lrow) * HID + ks * 32 + lk * 8);
            union { unsigned long long u[2]; bf16x8 v; } u;
            u.u[0] = ld_agent8(p);
            u.u[1] = ld_agent8(p + 8);
            a[ks] = u.v;
        }

        // ---- GEMM: gh = h @ whh^T, 3 gates x 2 col-frags
        f32x4 acc[3][2] = {};
#pragma unroll
        for (int ks = 0; ks < 16; ++ks) {
#pragma unroll
            for (int g = 0; g < 3; ++g) {
#pragma unroll
                for (int f = 0; f < 2; ++f) {
                    int row = g * 32 + f * 16 + lrow;
                    int sch = (ks * 4 + lk) ^ (row & 7);
                    bf16x8 b = *(const bf16x8*)(&wlds[row * 512 + sch * 8]);
                    acc[g][f] = __builtin_amdgcn_mfma_f32_16x16x32_bf16(a[ks], b, acc[g][f], 0, 0, 0);
                }
            }
        }

        // ---- gate math + state update (fp32, registers)
#pragma unroll
        for (int fj = 0; fj < 2; ++fj)
#pragma unroll
            for (int r = 0; r < 4; ++r) {
                float ghr = acc[0][fj][r] + bhhv[fj][0];
                float ghz = acc[1][fj][r] + bhhv[fj][1];
                float ghn = acc[2][fj][r] + bhhv[fj][2];
                float xr = gxv[fj][r][0] + bihv[fj][0];
                float xz = gxv[fj][r][1] + bihv[fj][1];
                float xn = gxv[fj][r][2] + bihv[fj][2];
                float rg_ = 1.f / (1.f + expf(-(xr + ghr)));
                float zg  = 1.f / (1.f + expf(-(xz + ghz)));
                float ng  = tanhf(xn + rg_ * ghn);
                float hn  = (1.f - zg) * ng + zg * hreg[fj][r];
                hreg[fj][r] = hn;
                if (t < mylen[r]) sreg[fj][r] += hn;
            }

        // ---- repack to rows in LDS, then coherent 8B stores to hnxt
#pragma unroll
        for (int fj = 0; fj < 2; ++fj)
#pragma unroll
            for (int r = 0; r < 4; ++r)
                hout[(wid * 16 + (lane >> 4) * 4 + r) * 32 + fj * 16 + (lane & 15)] =
                    (__bf16)hreg[fj][r];
        __syncthreads();
        {
            int row = threadIdx.x >> 2, ch = threadIdx.x & 3;
            unsigned long long* dst =
                (unsigned long long*)(hnxt + (size_t)(r0 + row) * HID + c0 + ch * 8);
            const unsigned long long* src = (const unsigned long long*)&hout[row * 32 + ch * 8];
            st_agent8(dst, src[0]);
            st_agent8(dst + 1, src[1]);
        }
        if (s + 1 == MAXL) break;   // no barrier needed after last step

        // all waves' coherent stores drain (vmcnt(0) at this barrier) before arrive
        __syncthreads();
        if (threadIdx.x == 0)
            __hip_atomic_fetch_add(ctr + grp * 32, 1u, __ATOMIC_RELAXED, __HIP_MEMORY_SCOPE_AGENT);

        // prefetch next step's gx while waiting (independent of the exchange)
        {
            int tn = dir ? (MAXL - 2 - s) : (s + 1);
#pragma unroll
            for (int r = 0; r < 4; ++r) {
                bool real = tn < mylen[r];
                size_t base = ((size_t)dir * N + mystart[r] + tn) * H3;
#pragma unroll
                for (int fj = 0; fj < 2; ++fj)
#pragma unroll
                    for (int g = 0; g < 3; ++g)
                        gxv[fj][r][g] = real ? (float)gx[base + (size_t)g * HID + mycol[fj]] : 0.f;
            }
        }

        if (threadIdx.x == 0) {
            unsigned tgt = 16u * (unsigned)(s + 1);
            while (__hip_atomic_load(ctr + grp * 32, __ATOMIC_RELAXED,
                                     __HIP_MEMORY_SCOPE_AGENT) < tgt)
                __builtin_amdgcn_s_sleep(1);
        }
        __syncthreads();
        asm volatile("" ::: "memory");       // compiler: no motion across the spin exit
        __builtin_amdgcn_sched_barrier(0);   // scheduler: keep next A-loads after it
    }

    // ---- final output: out[row][dir*H + col] = sum / len
#pragma unroll
    for (int fj = 0; fj < 2; ++fj)
#pragma unroll
        for (int r = 0; r < 4; ++r)
            out[(size_t)myrow[r] * (2 * HID) + (size_t)dir * HID + mycol[fj]] =
                sreg[fj][r] / (float)mylen[r];
}

extern "C" void kernel_launch(void* const* d_in, const int* in_sizes, int n_in,
                              void* d_out, int out_size, void* d_ws, size_t ws_size,
                              hipStream_t stream) {
    const float* h      = (const float*)d_in[0];
    const int*   lens   = (const int*)d_in[1];
    const float* bias   = (const float*)d_in[2];
    const float* w_ih_f = (const float*)d_in[3];
    const float* w_hh_f = (const float*)d_in[4];
    const float* b_ih_f = (const float*)d_in[5];
    const float* b_hh_f = (const float*)d_in[6];
    const float* w_ih_b = (const float*)d_in[7];
    const float* w_hh_b = (const float*)d_in[8];
    const float* b_ih_b = (const float*)d_in[9];
    const float* b_hh_b = (const float*)d_in[10];
    float* out = (float*)d_out;
    const int N = in_sizes[0] / HID;

    // workspace layout
    char* p = (char*)d_ws;
    size_t off = 0;
    int* starts   = (int*)(p + off);        off += 4096;
    unsigned* ctr = (unsigned*)(p + off);   off += 4096;   // 512 u32, groups 128B apart
    float* h0   = (float*)(p + off);        off += (size_t)BATCH * HID * 4;
    __bf16* hb  = (__bf16*)(p + off);       off += (size_t)2 * 2 * BATCH * HID * 2;
    __bf16* wih = (__bf16*)(p + off);       off += (size_t)2 * H3 * HID * 2;
    __bf16* whh = (__bf16*)(p + off);       off += (size_t)2 * H3 * HID * 2;
    __bf16* msg = (__bf16*)(p + off);       off += (size_t)N * HID * 2;
    __bf16* gx  = (__bf16*)(p + off);       off += (size_t)2 * N * H3 * 2;
    if (off > ws_size) return;  // interpretable failure: output stays zero

    scan_kernel<<<1, BATCH, 0, stream>>>(lens, starts, ctr);
    init_kernel<<<BATCH, HID, 0, stream>>>(h, lens, starts, h0, hb);

    long total4 = (long)N * HID / 4;
    int msgBlocks = (int)((total4 + 255) / 256); if (msgBlocks > 2048) msgBlocks = 2048;
    msg_kernel<<<msgBlocks, 256, 0, stream>>>(h, bias, msg, total4);

    int n4 = H3 * HID / 4;
    int cb = (n4 + 255) / 256;
    conv_kernel<<<cb, 256, 0, stream>>>(w_ih_f, wih, n4);
    conv_kernel<<<cb, 256, 0, stream>>>(w_ih_b, wih + (size_t)H3 * HID, n4);
    conv_kernel<<<cb, 256, 0, stream>>>(w_hh_f, whh, n4);
    conv_kernel<<<cb, 256, 0, stream>>>(w_hh_b, whh + (size_t)H3 * HID, n4);

    gx_gemm<<<dim3((N + 63) / 64, 2), 256, 0, stream>>>(msg, wih, gx, N);

    int Nv = N;
    void* kargs[] = {(void*)&whh, (void*)&gx, (void*)&h0, (void*)&hb,
                     (void*)&b_ih_f, (void*)&b_hh_f, (void*)&b_ih_b, (void*)&b_hh_b,
                     (void*)&lens, (void*)&starts, (void*)&ctr, (void*)&out, (void*)&Nv};
    hipLaunchCooperativeKernel((const void*)gru_scan, dim3(256), dim3(256), kargs, 0, stream);
}

// Round 6
// 1909.121 us; speedup vs baseline: 2.8157x; 1.0099x over previous
//
#include <hip/hip_runtime.h>
#include <hip/hip_bf16.h>
#include <math.h>

#define BATCH 512
#define MAXL 128
#define HID 512
#define H3 1536

typedef __bf16 bf16x8 __attribute__((ext_vector_type(8)));
typedef __bf16 bf16x4 __attribute__((ext_vector_type(4)));
typedef float f32x4 __attribute__((ext_vector_type(4)));

// agent-scope (device-coherent, fine-grained) load/store — bypass stale L1/L2,
// meet at the coherence point; RELAXED only (no acquire/release: those emit
// buffer_inv/buffer_wbl2 L2 maintenance on gfx950).
__device__ __forceinline__ void st_agent8(void* p, unsigned long long v) {
    __hip_atomic_store((unsigned long long*)p, v, __ATOMIC_RELAXED, __HIP_MEMORY_SCOPE_AGENT);
}
__device__ __forceinline__ unsigned long long ld_agent8(const void* p) {
    return __hip_atomic_load((const unsigned long long*)p, __ATOMIC_RELAXED, __HIP_MEMORY_SCOPE_AGENT);
}

// ---------------- prefix scan of lengths -> starts; zero barrier slots ----------------
__global__ __launch_bounds__(BATCH) void scan_kernel(const int* __restrict__ len,
                                                     int* __restrict__ starts,
                                                     unsigned* __restrict__ ctr) {
    __shared__ int buf[BATCH];
    int tid = threadIdx.x;
    ctr[tid] = 0u;                    // re-zeroed every launch (determinism across replays)
    int myLen = len[tid];
    buf[tid] = myLen;
    __syncthreads();
    for (int off = 1; off < BATCH; off <<= 1) {
        int v = (tid >= off) ? buf[tid - off] : 0;
        __syncthreads();
        buf[tid] += v;
        __syncthreads();
    }
    starts[tid] = buf[tid] - myLen;   // exclusive scan
}

// ------- h0 = segment_max(h) (fp32 + bf16 into scan buffer 0, both dirs) -------
__global__ __launch_bounds__(HID) void init_kernel(const float* __restrict__ h,
                                                   const int* __restrict__ len,
                                                   const int* __restrict__ starts,
                                                   float* __restrict__ h0,     // [B][H]
                                                   __bf16* __restrict__ hb) {  // buf0: [2][B][H]
    int b = blockIdx.x, j = threadIdx.x;
    int s = starts[b], L = len[b];
    float m = -3.4e38f;
    for (int t = 0; t < L; ++t) m = fmaxf(m, h[(size_t)(s + t) * HID + j]);
    h0[(size_t)b * HID + j] = m;
    hb[(size_t)b * HID + j] = (__bf16)m;
    hb[(size_t)(BATCH + b) * HID + j] = (__bf16)m;
}

// ---------------- message = relu(h + bias) -> bf16 ----------------
__global__ void msg_kernel(const float* __restrict__ h, const float* __restrict__ bias,
                           __bf16* __restrict__ msg, long total4) {
    for (long i = (long)blockIdx.x * blockDim.x + threadIdx.x; i < total4;
         i += (long)gridDim.x * blockDim.x) {
        float4 v = ((const float4*)h)[i];
        int c4 = (int)(i & (HID / 4 - 1));
        float4 bb = ((const float4*)bias)[c4];
        bf16x4 o;
        o[0] = (__bf16)fmaxf(v.x + bb.x, 0.f);
        o[1] = (__bf16)fmaxf(v.y + bb.y, 0.f);
        o[2] = (__bf16)fmaxf(v.z + bb.z, 0.f);
        o[3] = (__bf16)fmaxf(v.w + bb.w, 0.f);
        ((bf16x4*)msg)[i] = o;
    }
}

// ---------------- fp32 -> bf16 weight convert ----------------
__global__ void conv_kernel(const float* __restrict__ src, __bf16* __restrict__ dst, int n4) {
    int i = blockIdx.x * blockDim.x + threadIdx.x;
    if (i < n4) {
        float4 v = ((const float4*)src)[i];
        bf16x4 o;
        o[0] = (__bf16)v.x; o[1] = (__bf16)v.y; o[2] = (__bf16)v.z; o[3] = (__bf16)v.w;
        ((bf16x4*)dst)[i] = o;
    }
}

// ---------------- gx = msg @ w_ih^T  (NT GEMM, bf16 out) ----------------
__global__ __launch_bounds__(256) void gx_gemm(const __bf16* __restrict__ msg,
                                               const __bf16* __restrict__ wih,  // [2][1536][512]
                                               __bf16* __restrict__ gx,         // [2][N][1536]
                                               int N) {
    __shared__ __bf16 alds[64 * 512];    // 64KB, rows of 1KB, 16B-chunk XOR swizzle
    __shared__ __bf16 tile[64][136];     // 17KB output repack (row stride 272B, 16B-aligned)
    int dir = blockIdx.y;
    int r0 = blockIdx.x * 64;
    int wid = threadIdx.x >> 6, lane = threadIdx.x & 63;
    int lrow = lane & 15, lk = lane >> 4;
    const __bf16* wB = wih + (size_t)dir * H3 * HID;
    __bf16* gOut = gx + (size_t)dir * N * H3;

    // stage A (64 rows x 512 K) with swizzled 16B chunks
    for (int i = threadIdx.x; i < 64 * 64; i += 256) {
        int row = i >> 6, ch = i & 63;
        int sch = ch ^ (row & 7);
        int grow = r0 + row; if (grow >= N) grow = N - 1;
        *(bf16x8*)(&alds[row * 512 + sch * 8]) = *(const bf16x8*)(msg + (size_t)grow * HID + ch * 8);
    }
    __syncthreads();

    for (int ct = 0; ct < 12; ++ct) {
        int c0 = ct * 128 + wid * 32;    // this wave's 32 output cols
        f32x4 acc[4][2] = {};            // 4 row-frags x 2 col-frags
#pragma unroll
        for (int ks = 0; ks < 16; ++ks) {
            bf16x8 b0 = *(const bf16x8*)(wB + (size_t)(c0 + lrow) * HID + ks * 32 + lk * 8);
            bf16x8 b1 = *(const bf16x8*)(wB + (size_t)(c0 + 16 + lrow) * HID + ks * 32 + lk * 8);
#pragma unroll
            for (int rf = 0; rf < 4; ++rf) {
                int row = rf * 16 + lrow;
                int sch = (ks * 4 + lk) ^ (row & 7);
                bf16x8 av = *(const bf16x8*)(&alds[row * 512 + sch * 8]);
                acc[rf][0] = __builtin_amdgcn_mfma_f32_16x16x32_bf16(av, b0, acc[rf][0], 0, 0, 0);
                acc[rf][1] = __builtin_amdgcn_mfma_f32_16x16x32_bf16(av, b1, acc[rf][1], 0, 0, 0);
            }
        }
        __syncthreads();   // tile free from previous ct's readers
#pragma unroll
        for (int rf = 0; rf < 4; ++rf)
#pragma unroll
            for (int fj = 0; fj < 2; ++fj)
#pragma unroll
                for (int r = 0; r < 4; ++r)
                    tile[rf * 16 + (lane >> 4) * 4 + r][wid * 32 + fj * 16 + (lane & 15)] =
                        (__bf16)acc[rf][fj][r];
        __syncthreads();
        // 256 threads = 64 rows x 4 chunks of 32 cols; each thread writes ALL 32 cols
        int row = threadIdx.x >> 2, ch = threadIdx.x & 3;
        if (r0 + row < N) {
            __bf16* d = gOut + (size_t)(r0 + row) * H3 + ct * 128 + ch * 32;
            *(bf16x8*)(d)      = *(const bf16x8*)(&tile[row][ch * 32]);
            *(bf16x8*)(d + 8)  = *(const bf16x8*)(&tile[row][ch * 32 + 8]);
            *(bf16x8*)(d + 16) = *(const bf16x8*)(&tile[row][ch * 32 + 16]);
            *(bf16x8*)(d + 24) = *(const bf16x8*)(&tile[row][ch * 32 + 24]);
        }
    }
}

// ================= persistent GRU scan, slot-array 16-block barriers =================
// 256 blocks x 256 threads (coop launch for co-residency). Block = (dir, rg(8), hc(16)).
// Sync group = {dir, rg}. Arrive = relaxed 4B store of (s+1) into OWN slot (no RMW
// serialization); poll = lanes 0..15 each watch one slot of the group's 64B line
// (one coalesced transaction per poll iteration). Ordering: __syncthreads drains
// vmcnt(0) before the arrive store; control dep + clobbers order the resume.
__global__ __launch_bounds__(256, 1) void gru_scan(
    const __bf16* __restrict__ whh,   // [2][1536][512]
    const __bf16* __restrict__ gx,    // [2][N][1536]
    const float* __restrict__ h0,     // [B][H]
    __bf16* __restrict__ hb,          // [2 bufs][2 dirs][B][H]
    const float* __restrict__ b_ih_f, const float* __restrict__ b_hh_f,
    const float* __restrict__ b_ih_b, const float* __restrict__ b_hh_b,
    const int* __restrict__ len, const int* __restrict__ starts,
    unsigned* __restrict__ ctr,       // [16 groups][16 slots] u32, 64B per group
    float* __restrict__ out, int N) {

    __shared__ __bf16 wlds[96 * 512];   // 96KB weight tile, 16B-chunk XOR swizzle
    __shared__ __bf16 hout[64 * 40];    // 5KB repack tile (80B row stride: fewer conflicts)

    int bid = blockIdx.x;
    int rg  = bid & 7;                  // same rg -> same XCD (heuristic; not required)
    int dir = (bid >> 3) & 1;
    int hc  = bid >> 4;
    int grp = dir * 8 + rg;
    int wid = threadIdx.x >> 6, lane = threadIdx.x & 63;
    int r0 = rg * 64;
    int c0 = hc * 32;

    for (int i = threadIdx.x; i < 96 * 64; i += 256) {
        int row = i >> 6, ch = i & 63;
        int g = row >> 5, c = row & 31;
        int sch = ch ^ (row & 7);
        const __bf16* src = whh + ((size_t)dir * H3 + (size_t)g * HID + c0 + c) * HID + ch * 8;
        *(bf16x8*)(&wlds[row * 512 + sch * 8]) = *(const bf16x8*)src;
    }

    int wr0 = r0 + wid * 16;
    int lrow = lane & 15;
    int lk   = lane >> 4;

    int mycol[2], myrow[4];
#pragma unroll
    for (int fj = 0; fj < 2; ++fj) mycol[fj] = c0 + fj * 16 + (lane & 15);
#pragma unroll
    for (int r = 0; r < 4; ++r) myrow[r] = wr0 + (lane >> 4) * 4 + r;

    float hreg[2][4], sreg[2][4];
#pragma unroll
    for (int fj = 0; fj < 2; ++fj)
#pragma unroll
        for (int r = 0; r < 4; ++r) {
            hreg[fj][r] = h0[(size_t)myrow[r] * HID + mycol[fj]];
            sreg[fj][r] = 0.f;
        }

    const float* bih = dir ? b_ih_b : b_ih_f;
    const float* bhh = dir ? b_hh_b : b_hh_f;
    float bihv[2][3], bhhv[2][3];
#pragma unroll
    for (int fj = 0; fj < 2; ++fj)
#pragma unroll
        for (int g = 0; g < 3; ++g) {
            bihv[fj][g] = bih[g * HID + mycol[fj]];
            bhhv[fj][g] = bhh[g * HID + mycol[fj]];
        }
    int mylen[4], mystart[4];
#pragma unroll
    for (int r = 0; r < 4; ++r) { mylen[r] = len[myrow[r]]; mystart[r] = starts[myrow[r]]; }

    // prefetch gx for step 0
    float gxv[2][4][3];
    {
        int t = dir ? (MAXL - 1) : 0;
#pragma unroll
        for (int r = 0; r < 4; ++r) {
            bool real = t < mylen[r];
            size_t base = ((size_t)dir * N + mystart[r] + t) * H3;
#pragma unroll
            for (int fj = 0; fj < 2; ++fj)
#pragma unroll
                for (int g = 0; g < 3; ++g)
                    gxv[fj][r][g] = real ? (float)gx[base + (size_t)g * HID + mycol[fj]] : 0.f;
        }
    }

    __syncthreads();   // wlds ready

    const size_t bufStride = (size_t)2 * BATCH * HID;

    for (int s = 0; s < MAXL; ++s) {
        int t = dir ? (MAXL - 1 - s) : s;
        const __bf16* hcur = hb + (size_t)(s & 1) * bufStride + (size_t)dir * BATCH * HID;
        __bf16* hnxt = hb + (size_t)((s + 1) & 1) * bufStride + (size_t)dir * BATCH * HID;

        // ---- A: this wave's [16 rows x 512 K] via coherent 8B loads
        bf16x8 a[16];
#pragma unroll
        for (int ks = 0; ks < 16; ++ks) {
            const char* p = (const char*)(hcur + (size_t)(wr0 + lrow) * HID + ks * 32 + lk * 8);
            union { unsigned long long u[2]; bf16x8 v; } u;
            u.u[0] = ld_agent8(p);
            u.u[1] = ld_agent8(p + 8);
            a[ks] = u.v;
        }

        // ---- GEMM: gh = h @ whh^T, 3 gates x 2 col-frags
        f32x4 acc[3][2] = {};
#pragma unroll
        for (int ks = 0; ks < 16; ++ks) {
#pragma unroll
            for (int g = 0; g < 3; ++g) {
#pragma unroll
                for (int f = 0; f < 2; ++f) {
                    int row = g * 32 + f * 16 + lrow;
                    int sch = (ks * 4 + lk) ^ (row & 7);
                    bf16x8 b = *(const bf16x8*)(&wlds[row * 512 + sch * 8]);
                    acc[g][f] = __builtin_amdgcn_mfma_f32_16x16x32_bf16(a[ks], b, acc[g][f], 0, 0, 0);
                }
            }
        }

        // ---- gate math + state update (fp32, registers)
#pragma unroll
        for (int fj = 0; fj < 2; ++fj)
#pragma unroll
            for (int r = 0; r < 4; ++r) {
                float ghr = acc[0][fj][r] + bhhv[fj][0];
                float ghz = acc[1][fj][r] + bhhv[fj][1];
                float ghn = acc[2][fj][r] + bhhv[fj][2];
                float xr = gxv[fj][r][0] + bihv[fj][0];
                float xz = gxv[fj][r][1] + bihv[fj][1];
                float xn = gxv[fj][r][2] + bihv[fj][2];
                float rg_ = 1.f / (1.f + expf(-(xr + ghr)));
                float zg  = 1.f / (1.f + expf(-(xz + ghz)));
                float ng  = tanhf(xn + rg_ * ghn);
                float hn  = (1.f - zg) * ng + zg * hreg[fj][r];
                hreg[fj][r] = hn;
                if (t < mylen[r]) sreg[fj][r] += hn;
            }

        // ---- repack to rows in LDS, then coherent 8B stores to hnxt
#pragma unroll
        for (int fj = 0; fj < 2; ++fj)
#pragma unroll
            for (int r = 0; r < 4; ++r)
                hout[(wid * 16 + (lane >> 4) * 4 + r) * 40 + fj * 16 + (lane & 15)] =
                    (__bf16)hreg[fj][r];
        __syncthreads();
        {
            int row = threadIdx.x >> 2, ch = threadIdx.x & 3;
            unsigned long long* dst =
                (unsigned long long*)(hnxt + (size_t)(r0 + row) * HID + c0 + ch * 8);
            const unsigned long long* src = (const unsigned long long*)&hout[row * 40 + ch * 8];
            st_agent8(dst, src[0]);
            st_agent8(dst + 1, src[1]);
        }
        if (s + 1 == MAXL) break;   // no barrier needed after last step

        // all waves' coherent stores drain (vmcnt(0) at this barrier) before arrive
        __syncthreads();
        if (threadIdx.x == 0)
            __hip_atomic_store(ctr + grp * 16 + hc, (unsigned)(s + 1),
                               __ATOMIC_RELAXED, __HIP_MEMORY_SCOPE_AGENT);

        // prefetch next step's gx while waiting (independent of the exchange)
        {
            int tn = dir ? (MAXL - 2 - s) : (s + 1);
#pragma unroll
            for (int r = 0; r < 4; ++r) {
                bool real = tn < mylen[r];
                size_t base = ((size_t)dir * N + mystart[r] + tn) * H3;
#pragma unroll
                for (int fj = 0; fj < 2; ++fj)
#pragma unroll
                    for (int g = 0; g < 3; ++g)
                        gxv[fj][r][g] = real ? (float)gx[base + (size_t)g * HID + mycol[fj]] : 0.f;
            }
        }

        // poll: lanes 0..15 each watch one slot (one 64B line -> 1 txn per iteration)
        if (threadIdx.x < 16) {
            unsigned tgt = (unsigned)(s + 1);
            while (__hip_atomic_load(ctr + grp * 16 + threadIdx.x, __ATOMIC_RELAXED,
                                     __HIP_MEMORY_SCOPE_AGENT) < tgt)
                __builtin_amdgcn_s_sleep(1);
        }
        __syncthreads();
        asm volatile("" ::: "memory");       // compiler: no motion across the spin exit
        __builtin_amdgcn_sched_barrier(0);   // scheduler: keep next A-loads after it
    }

    // ---- final output: out[row][dir*H + col] = sum / len
#pragma unroll
    for (int fj = 0; fj < 2; ++fj)
#pragma unroll
        for (int r = 0; r < 4; ++r)
            out[(size_t)myrow[r] * (2 * HID) + (size_t)dir * HID + mycol[fj]] =
                sreg[fj][r] / (float)mylen[r];
}

extern "C" void kernel_launch(void* const* d_in, const int* in_sizes, int n_in,
                              void* d_out, int out_size, void* d_ws, size_t ws_size,
                              hipStream_t stream) {
    const float* h      = (const float*)d_in[0];
    const int*   lens   = (const int*)d_in[1];
    const float* bias   = (const float*)d_in[2];
    const float* w_ih_f = (const float*)d_in[3];
    const float* w_hh_f = (const float*)d_in[4];
    const float* b_ih_f = (const float*)d_in[5];
    const float* b_hh_f = (const float*)d_in[6];
    const float* w_ih_b = (const float*)d_in[7];
    const float* w_hh_b = (const float*)d_in[8];
    const float* b_ih_b = (const float*)d_in[9];
    const float* b_hh_b = (const float*)d_in[10];
    float* out = (float*)d_out;
    const int N = in_sizes[0] / HID;

    // workspace layout
    char* p = (char*)d_ws;
    size_t off = 0;
    int* starts   = (int*)(p + off);        off += 4096;
    unsigned* ctr = (unsigned*)(p + off);   off += 4096;   // 16 groups x 16 slots, 64B/group
    float* h0   = (float*)(p + off);        off += (size_t)BATCH * HID * 4;
    __bf16* hb  = (__bf16*)(p + off);       off += (size_t)2 * 2 * BATCH * HID * 2;
    __bf16* wih = (__bf16*)(p + off);       off += (size_t)2 * H3 * HID * 2;
    __bf16* whh = (__bf16*)(p + off);       off += (size_t)2 * H3 * HID * 2;
    __bf16* msg = (__bf16*)(p + off);       off += (size_t)N * HID * 2;
    __bf16* gx  = (__bf16*)(p + off);       off += (size_t)2 * N * H3 * 2;
    if (off > ws_size) return;  // interpretable failure: output stays zero

    scan_kernel<<<1, BATCH, 0, stream>>>(lens, starts, ctr);
    init_kernel<<<BATCH, HID, 0, stream>>>(h, lens, starts, h0, hb);

    long total4 = (long)N * HID / 4;
    int msgBlocks = (int)((total4 + 255) / 256); if (msgBlocks > 2048) msgBlocks = 2048;
    msg_kernel<<<msgBlocks, 256, 0, stream>>>(h, bias, msg, total4);

    int n4 = H3 * HID / 4;
    int cb = (n4 + 255) / 256;
    conv_kernel<<<cb, 256, 0, stream>>>(w_ih_f, wih, n4);
    conv_kernel<<<cb, 256, 0, stream>>>(w_ih_b, wih + (size_t)H3 * HID, n4);
    conv_kernel<<<cb, 256, 0, stream>>>(w_hh_f, whh, n4);
    conv_kernel<<<cb, 256, 0, stream>>>(w_hh_b, whh + (size_t)H3 * HID, n4);

    gx_gemm<<<dim3((N + 63) / 64, 2), 256, 0, stream>>>(msg, wih, gx, N);

    int Nv = N;
    void* kargs[] = {(void*)&whh, (void*)&gx, (void*)&h0, (void*)&hb,
                     (void*)&b_ih_f, (void*)&b_hh_f, (void*)&b_ih_b, (void*)&b_hh_b,
                     (void*)&lens, (void*)&starts, (void*)&ctr, (void*)&out, (void*)&Nv};
    hipLaunchCooperativeKernel((const void*)gru_scan, dim3(256), dim3(256), kargs, 0, stream);
}

// Round 7
// 1832.485 us; speedup vs baseline: 2.9335x; 1.0418x over previous
//
#include <hip/hip_runtime.h>
#include <hip/hip_bf16.h>
#include <math.h>

#define BATCH 512
#define MAXL 128
#define HID 512
#define H3 1536

typedef __bf16 bf16x8 __attribute__((ext_vector_type(8)));
typedef __bf16 bf16x4 __attribute__((ext_vector_type(4)));
typedef float f32x4 __attribute__((ext_vector_type(4)));

// ---------------- prefix scan of lengths -> starts; zero barrier slots ----------------
__global__ __launch_bounds__(BATCH) void scan_kernel(const int* __restrict__ len,
                                                     int* __restrict__ starts,
                                                     unsigned* __restrict__ ctr) {
    __shared__ int buf[BATCH];
    int tid = threadIdx.x;
    ctr[tid] = 0u;                    // re-zeroed every launch (determinism across replays)
    int myLen = len[tid];
    buf[tid] = myLen;
    __syncthreads();
    for (int off = 1; off < BATCH; off <<= 1) {
        int v = (tid >= off) ? buf[tid - off] : 0;
        __syncthreads();
        buf[tid] += v;
        __syncthreads();
    }
    starts[tid] = buf[tid] - myLen;   // exclusive scan
}

// ------- h0 = segment_max(h) (fp32 + bf16 into scan buffer 0, both dirs) -------
__global__ __launch_bounds__(HID) void init_kernel(const float* __restrict__ h,
                                                   const int* __restrict__ len,
                                                   const int* __restrict__ starts,
                                                   float* __restrict__ h0,     // [B][H]
                                                   __bf16* __restrict__ hb) {  // buf0: [2][B][H]
    int b = blockIdx.x, j = threadIdx.x;
    int s = starts[b], L = len[b];
    float m = -3.4e38f;
    for (int t = 0; t < L; ++t) m = fmaxf(m, h[(size_t)(s + t) * HID + j]);
    h0[(size_t)b * HID + j] = m;
    hb[(size_t)b * HID + j] = (__bf16)m;
    hb[(size_t)(BATCH + b) * HID + j] = (__bf16)m;
}

// ---------------- message = relu(h + bias) -> bf16 ----------------
__global__ void msg_kernel(const float* __restrict__ h, const float* __restrict__ bias,
                           __bf16* __restrict__ msg, long total4) {
    for (long i = (long)blockIdx.x * blockDim.x + threadIdx.x; i < total4;
         i += (long)gridDim.x * blockDim.x) {
        float4 v = ((const float4*)h)[i];
        int c4 = (int)(i & (HID / 4 - 1));
        float4 bb = ((const float4*)bias)[c4];
        bf16x4 o;
        o[0] = (__bf16)fmaxf(v.x + bb.x, 0.f);
        o[1] = (__bf16)fmaxf(v.y + bb.y, 0.f);
        o[2] = (__bf16)fmaxf(v.z + bb.z, 0.f);
        o[3] = (__bf16)fmaxf(v.w + bb.w, 0.f);
        ((bf16x4*)msg)[i] = o;
    }
}

// ---------------- fp32 -> bf16 weight convert ----------------
__global__ void conv_kernel(const float* __restrict__ src, __bf16* __restrict__ dst, int n4) {
    int i = blockIdx.x * blockDim.x + threadIdx.x;
    if (i < n4) {
        float4 v = ((const float4*)src)[i];
        bf16x4 o;
        o[0] = (__bf16)v.x; o[1] = (__bf16)v.y; o[2] = (__bf16)v.z; o[3] = (__bf16)v.w;
        ((bf16x4*)dst)[i] = o;
    }
}

// ---------------- gx = msg @ w_ih^T  (NT GEMM, bf16 out) ----------------
__global__ __launch_bounds__(256) void gx_gemm(const __bf16* __restrict__ msg,
                                               const __bf16* __restrict__ wih,  // [2][1536][512]
                                               __bf16* __restrict__ gx,         // [2][N][1536]
                                               int N) {
    __shared__ __bf16 alds[64 * 512];    // 64KB, rows of 1KB, 16B-chunk XOR swizzle
    __shared__ __bf16 tile[64][136];     // 17KB output repack (row stride 272B, 16B-aligned)
    int dir = blockIdx.y;
    int r0 = blockIdx.x * 64;
    int wid = threadIdx.x >> 6, lane = threadIdx.x & 63;
    int lrow = lane & 15, lk = lane >> 4;
    const __bf16* wB = wih + (size_t)dir * H3 * HID;
    __bf16* gOut = gx + (size_t)dir * N * H3;

    // stage A (64 rows x 512 K) with swizzled 16B chunks
    for (int i = threadIdx.x; i < 64 * 64; i += 256) {
        int row = i >> 6, ch = i & 63;
        int sch = ch ^ (row & 7);
        int grow = r0 + row; if (grow >= N) grow = N - 1;
        *(bf16x8*)(&alds[row * 512 + sch * 8]) = *(const bf16x8*)(msg + (size_t)grow * HID + ch * 8);
    }
    __syncthreads();

    for (int ct = 0; ct < 12; ++ct) {
        int c0 = ct * 128 + wid * 32;    // this wave's 32 output cols
        f32x4 acc[4][2] = {};            // 4 row-frags x 2 col-frags
#pragma unroll
        for (int ks = 0; ks < 16; ++ks) {
            bf16x8 b0 = *(const bf16x8*)(wB + (size_t)(c0 + lrow) * HID + ks * 32 + lk * 8);
            bf16x8 b1 = *(const bf16x8*)(wB + (size_t)(c0 + 16 + lrow) * HID + ks * 32 + lk * 8);
#pragma unroll
            for (int rf = 0; rf < 4; ++rf) {
                int row = rf * 16 + lrow;
                int sch = (ks * 4 + lk) ^ (row & 7);
                bf16x8 av = *(const bf16x8*)(&alds[row * 512 + sch * 8]);
                acc[rf][0] = __builtin_amdgcn_mfma_f32_16x16x32_bf16(av, b0, acc[rf][0], 0, 0, 0);
                acc[rf][1] = __builtin_amdgcn_mfma_f32_16x16x32_bf16(av, b1, acc[rf][1], 0, 0, 0);
            }
        }
        __syncthreads();   // tile free from previous ct's readers
#pragma unroll
        for (int rf = 0; rf < 4; ++rf)
#pragma unroll
            for (int fj = 0; fj < 2; ++fj)
#pragma unroll
                for (int r = 0; r < 4; ++r)
                    tile[rf * 16 + (lane >> 4) * 4 + r][wid * 32 + fj * 16 + (lane & 15)] =
                        (__bf16)acc[rf][fj][r];
        __syncthreads();
        // 256 threads = 64 rows x 4 chunks of 32 cols; each thread writes ALL 32 cols
        int row = threadIdx.x >> 2, ch = threadIdx.x & 3;
        if (r0 + row < N) {
            __bf16* d = gOut + (size_t)(r0 + row) * H3 + ct * 128 + ch * 32;
            *(bf16x8*)(d)      = *(const bf16x8*)(&tile[row][ch * 32]);
            *(bf16x8*)(d + 8)  = *(const bf16x8*)(&tile[row][ch * 32 + 8]);
            *(bf16x8*)(d + 16) = *(const bf16x8*)(&tile[row][ch * 32 + 16]);
            *(bf16x8*)(d + 24) = *(const bf16x8*)(&tile[row][ch * 32 + 24]);
        }
    }
}

// ================= persistent GRU scan, slot-array 16-block barriers =================
// Data exchange now uses PLAIN global_load/store_dwordx4 with sc0 sc1 (device-coherent,
// bypass stale L1/L2, meet at the coherence point) — NOT atomics: atomics can't be
// merged/pipelined by the compiler and were suspected of serializing at MALL latency.
// Explicit s_waitcnt vmcnt(0) after asm load batch (+sched_barrier, rule 18) and after
// the asm store phase (asm VMEM isn't compiler-tracked).
__global__ __launch_bounds__(256, 1) void gru_scan(
    const __bf16* __restrict__ whh,   // [2][1536][512]
    const __bf16* __restrict__ gx,    // [2][N][1536]
    const float* __restrict__ h0,     // [B][H]
    __bf16* __restrict__ hb,          // [2 bufs][2 dirs][B][H]
    const float* __restrict__ b_ih_f, const float* __restrict__ b_hh_f,
    const float* __restrict__ b_ih_b, const float* __restrict__ b_hh_b,
    const int* __restrict__ len, const int* __restrict__ starts,
    unsigned* __restrict__ ctr,       // [16 groups][16 slots] u32, 64B per group
    float* __restrict__ out, int N) {

    __shared__ __bf16 wlds[96 * 512];   // 96KB weight tile, 16B-chunk XOR swizzle
    __shared__ __bf16 hout[64 * 40];    // 5KB repack tile (80B row stride)

    int bid = blockIdx.x;
    int rg  = bid & 7;
    int dir = (bid >> 3) & 1;
    int hc  = bid >> 4;
    int grp = dir * 8 + rg;
    int wid = threadIdx.x >> 6, lane = threadIdx.x & 63;
    int r0 = rg * 64;
    int c0 = hc * 32;

    for (int i = threadIdx.x; i < 96 * 64; i += 256) {
        int row = i >> 6, ch = i & 63;
        int g = row >> 5, c = row & 31;
        int sch = ch ^ (row & 7);
        const __bf16* src = whh + ((size_t)dir * H3 + (size_t)g * HID + c0 + c) * HID + ch * 8;
        *(bf16x8*)(&wlds[row * 512 + sch * 8]) = *(const bf16x8*)src;
    }

    int wr0 = r0 + wid * 16;
    int lrow = lane & 15;
    int lk   = lane >> 4;

    int mycol[2], myrow[4];
#pragma unroll
    for (int fj = 0; fj < 2; ++fj) mycol[fj] = c0 + fj * 16 + (lane & 15);
#pragma unroll
    for (int r = 0; r < 4; ++r) myrow[r] = wr0 + (lane >> 4) * 4 + r;

    float hreg[2][4], sreg[2][4];
#pragma unroll
    for (int fj = 0; fj < 2; ++fj)
#pragma unroll
        for (int r = 0; r < 4; ++r) {
            hreg[fj][r] = h0[(size_t)myrow[r] * HID + mycol[fj]];
            sreg[fj][r] = 0.f;
        }

    const float* bih = dir ? b_ih_b : b_ih_f;
    const float* bhh = dir ? b_hh_b : b_hh_f;
    float bihv[2][3], bhhv[2][3];
#pragma unroll
    for (int fj = 0; fj < 2; ++fj)
#pragma unroll
        for (int g = 0; g < 3; ++g) {
            bihv[fj][g] = bih[g * HID + mycol[fj]];
            bhhv[fj][g] = bhh[g * HID + mycol[fj]];
        }
    int mylen[4], mystart[4];
#pragma unroll
    for (int r = 0; r < 4; ++r) { mylen[r] = len[myrow[r]]; mystart[r] = starts[myrow[r]]; }

    // prefetch gx for step 0
    float gxv[2][4][3];
    {
        int t = dir ? (MAXL - 1) : 0;
#pragma unroll
        for (int r = 0; r < 4; ++r) {
            bool real = t < mylen[r];
            size_t base = ((size_t)dir * N + mystart[r] + t) * H3;
#pragma unroll
            for (int fj = 0; fj < 2; ++fj)
#pragma unroll
                for (int g = 0; g < 3; ++g)
                    gxv[fj][r][g] = real ? (float)gx[base + (size_t)g * HID + mycol[fj]] : 0.f;
        }
    }

    __syncthreads();   // wlds ready

    const size_t bufStride = (size_t)2 * BATCH * HID;

    for (int s = 0; s < MAXL; ++s) {
        int t = dir ? (MAXL - 1 - s) : s;
        const __bf16* hcur = hb + (size_t)(s & 1) * bufStride + (size_t)dir * BATCH * HID;
        __bf16* hnxt = hb + (size_t)((s + 1) & 1) * bufStride + (size_t)dir * BATCH * HID;

        // ---- A: this wave's [16 rows x 512 K] via coherent 16B loads (sc0 sc1),
        //      all 16 in flight, one waitcnt at the end
        bf16x8 a[16];
#pragma unroll
        for (int ks = 0; ks < 16; ++ks) {
            const __bf16* p = hcur + (size_t)(wr0 + lrow) * HID + ks * 32 + lk * 8;
            asm volatile("global_load_dwordx4 %0, %1, off sc0 sc1"
                         : "=v"(a[ks]) : "v"((const void*)p) : "memory");
        }
        asm volatile("s_waitcnt vmcnt(0)" ::: "memory");
        __builtin_amdgcn_sched_barrier(0);   // keep MFMAs below the waitcnt (rule 18)

        // ---- GEMM: gh = h @ whh^T, 3 gates x 2 col-frags
        f32x4 acc[3][2] = {};
#pragma unroll
        for (int ks = 0; ks < 16; ++ks) {
#pragma unroll
            for (int g = 0; g < 3; ++g) {
#pragma unroll
                for (int f = 0; f < 2; ++f) {
                    int row = g * 32 + f * 16 + lrow;
                    int sch = (ks * 4 + lk) ^ (row & 7);
                    bf16x8 b = *(const bf16x8*)(&wlds[row * 512 + sch * 8]);
                    acc[g][f] = __builtin_amdgcn_mfma_f32_16x16x32_bf16(a[ks], b, acc[g][f], 0, 0, 0);
                }
            }
        }

        // ---- gate math + state update (fp32, registers)
#pragma unroll
        for (int fj = 0; fj < 2; ++fj)
#pragma unroll
            for (int r = 0; r < 4; ++r) {
                float ghr = acc[0][fj][r] + bhhv[fj][0];
                float ghz = acc[1][fj][r] + bhhv[fj][1];
                float ghn = acc[2][fj][r] + bhhv[fj][2];
                float xr = gxv[fj][r][0] + bihv[fj][0];
                float xz = gxv[fj][r][1] + bihv[fj][1];
                float xn = gxv[fj][r][2] + bihv[fj][2];
                float rg_ = 1.f / (1.f + expf(-(xr + ghr)));
                float zg  = 1.f / (1.f + expf(-(xz + ghz)));
                float ng  = tanhf(xn + rg_ * ghn);
                float hn  = (1.f - zg) * ng + zg * hreg[fj][r];
                hreg[fj][r] = hn;
                if (t < mylen[r]) sreg[fj][r] += hn;
            }

        // ---- repack to rows in LDS, then coherent 16B stores to hnxt
#pragma unroll
        for (int fj = 0; fj < 2; ++fj)
#pragma unroll
            for (int r = 0; r < 4; ++r)
                hout[(wid * 16 + (lane >> 4) * 4 + r) * 40 + fj * 16 + (lane & 15)] =
                    (__bf16)hreg[fj][r];
        __syncthreads();
        {
            int row = threadIdx.x >> 2, ch = threadIdx.x & 3;
            __bf16* dst = hnxt + (size_t)(r0 + row) * HID + c0 + ch * 8;
            bf16x8 v = *(const bf16x8*)(&hout[row * 40 + ch * 8]);
            asm volatile("global_store_dwordx4 %0, %1, off sc0 sc1"
                         :: "v"((void*)dst), "v"(v) : "memory");
        }
        if (s + 1 == MAXL) break;   // no barrier needed after last step

        // drain asm stores (not compiler-tracked), then block-wide rendezvous, then arrive
        asm volatile("s_waitcnt vmcnt(0)" ::: "memory");
        __syncthreads();
        if (threadIdx.x == 0)
            __hip_atomic_store(ctr + grp * 16 + hc, (unsigned)(s + 1),
                               __ATOMIC_RELAXED, __HIP_MEMORY_SCOPE_AGENT);

        // prefetch next step's gx while waiting (independent of the exchange)
        {
            int tn = dir ? (MAXL - 2 - s) : (s + 1);
#pragma unroll
            for (int r = 0; r < 4; ++r) {
                bool real = tn < mylen[r];
                size_t base = ((size_t)dir * N + mystart[r] + tn) * H3;
#pragma unroll
                for (int fj = 0; fj < 2; ++fj)
#pragma unroll
                    for (int g = 0; g < 3; ++g)
                        gxv[fj][r][g] = real ? (float)gx[base + (size_t)g * HID + mycol[fj]] : 0.f;
            }
        }

        // poll: lanes 0..15 each watch one slot (one 64B line -> 1 txn per iteration)
        if (threadIdx.x < 16) {
            unsigned tgt = (unsigned)(s + 1);
            while (__hip_atomic_load(ctr + grp * 16 + threadIdx.x, __ATOMIC_RELAXED,
                                     __HIP_MEMORY_SCOPE_AGENT) < tgt)
                __builtin_amdgcn_s_sleep(1);
        }
        __syncthreads();
        asm volatile("" ::: "memory");       // compiler: no motion across the spin exit
        __builtin_amdgcn_sched_barrier(0);   // scheduler: keep next A-loads after it
    }

    // ---- final output: out[row][dir*H + col] = sum / len
#pragma unroll
    for (int fj = 0; fj < 2; ++fj)
#pragma unroll
        for (int r = 0; r < 4; ++r)
            out[(size_t)myrow[r] * (2 * HID) + (size_t)dir * HID + mycol[fj]] =
                sreg[fj][r] / (float)mylen[r];
}

extern "C" void kernel_launch(void* const* d_in, const int* in_sizes, int n_in,
                              void* d_out, int out_size, void* d_ws, size_t ws_size,
                              hipStream_t stream) {
    const float* h      = (const float*)d_in[0];
    const int*   lens   = (const int*)d_in[1];
    const float* bias   = (const float*)d_in[2];
    const float* w_ih_f = (const float*)d_in[3];
    const float* w_hh_f = (const float*)d_in[4];
    const float* b_ih_f = (const float*)d_in[5];
    const float* b_hh_f = (const float*)d_in[6];
    const float* w_ih_b = (const float*)d_in[7];
    const float* w_hh_b = (const float*)d_in[8];
    const float* b_ih_b = (const float*)d_in[9];
    const float* b_hh_b = (const float*)d_in[10];
    float* out = (float*)d_out;
    const int N = in_sizes[0] / HID;

    // workspace layout
    char* p = (char*)d_ws;
    size_t off = 0;
    int* starts   = (int*)(p + off);        off += 4096;
    unsigned* ctr = (unsigned*)(p + off);   off += 4096;   // 16 groups x 16 slots, 64B/group
    float* h0   = (float*)(p + off);        off += (size_t)BATCH * HID * 4;
    __bf16* hb  = (__bf16*)(p + off);       off += (size_t)2 * 2 * BATCH * HID * 2;
    __bf16* wih = (__bf16*)(p + off);       off += (size_t)2 * H3 * HID * 2;
    __bf16* whh = (__bf16*)(p + off);       off += (size_t)2 * H3 * HID * 2;
    __bf16* msg = (__bf16*)(p + off);       off += (size_t)N * HID * 2;
    __bf16* gx  = (__bf16*)(p + off);       off += (size_t)2 * N * H3 * 2;
    if (off > ws_size) return;  // interpretable failure: output stays zero

    scan_kernel<<<1, BATCH, 0, stream>>>(lens, starts, ctr);
    init_kernel<<<BATCH, HID, 0, stream>>>(h, lens, starts, h0, hb);

    long total4 = (long)N * HID / 4;
    int msgBlocks = (int)((total4 + 255) / 256); if (msgBlocks > 2048) msgBlocks = 2048;
    msg_kernel<<<msgBlocks, 256, 0, stream>>>(h, bias, msg, total4);

    int n4 = H3 * HID / 4;
    int cb = (n4 + 255) / 256;
    conv_kernel<<<cb, 256, 0, stream>>>(w_ih_f, wih, n4);
    conv_kernel<<<cb, 256, 0, stream>>>(w_ih_b, wih + (size_t)H3 * HID, n4);
    conv_kernel<<<cb, 256, 0, stream>>>(w_hh_f, whh, n4);
    conv_kernel<<<cb, 256, 0, stream>>>(w_hh_b, whh + (size_t)H3 * HID, n4);

    gx_gemm<<<dim3((N + 63) / 64, 2), 256, 0, stream>>>(msg, wih, gx, N);

    int Nv = N;
    void* kargs[] = {(void*)&whh, (void*)&gx, (void*)&h0, (void*)&hb,
                     (void*)&b_ih_f, (void*)&b_hh_f, (void*)&b_ih_b, (void*)&b_hh_b,
                     (void*)&lens, (void*)&starts, (void*)&ctr, (void*)&out, (void*)&Nv};
    hipLaunchCooperativeKernel((const void*)gru_scan, dim3(256), dim3(256), kargs, 0, stream);
}